// Round 11
// baseline (188.234 us; speedup 1.0000x reference)
//
#include <hip/hip_runtime.h>
#include <hip/hip_bf16.h>

// Problem constants: B=2, S=2048, H=16, dk=64, D_MODEL=1024, THETA=10000
// Packed fragment layouts (consumed by attn6, produced by the fused GEMM epilogue):
//   Qf/Kf[bh][t][j][lane][e]  = X[bh][t*32 + (lane&31)][j*16 + (lane>>5)*8 + e]
//   Vf[bh][t][seg][lane][e]   = V[bh][t*32 + (seg&1)*16 + (lane>>5)*8 + e][(seg>>1)*32 + (lane&31)]
// Round 11: round-10 fusion with the t-index fix: t = ((row>>5) & 63) — tile index
// is PER-bh; round 10 used the global row tile (0..127) which double-counted batch.

using u16 = unsigned short;
typedef __attribute__((ext_vector_type(8))) short short8;
typedef __attribute__((ext_vector_type(4))) float f32x4;
typedef __attribute__((ext_vector_type(16))) float f32x16;
typedef __attribute__((ext_vector_type(2))) unsigned uint2v;
typedef __attribute__((ext_vector_type(4))) unsigned uint4v;

__device__ __forceinline__ float bf2f(u16 v) {
  unsigned u = ((unsigned)v) << 16; float f; __builtin_memcpy(&f, &u, 4); return f;
}
__device__ __forceinline__ u16 f2bf(float f) {
  unsigned u; __builtin_memcpy(&u, &f, 4);
  return (u16)((u + 0x7fffu + ((u >> 16) & 1u)) >> 16);
}
__device__ __forceinline__ float u2f(unsigned u) {
  float f; __builtin_memcpy(&f, &u, 4); return f;
}
__device__ __forceinline__ unsigned f2u(float f) {
  unsigned u; __builtin_memcpy(&u, &f, 4); return u;
}
__device__ __forceinline__ float xhalf_max(float x) {
  uint2v s = __builtin_amdgcn_permlane32_swap(f2u(x), f2u(x), false, false);
  unsigned ax = s.x, bx = s.y;
  return fmaxf(u2f(ax), u2f(bx));
}
__device__ __forceinline__ float xhalf_sum(float x) {
  uint2v s = __builtin_amdgcn_permlane32_swap(f2u(x), f2u(x), false, false);
  unsigned ax = s.x, bx = s.y;
  return u2f(ax) + u2f(bx);
}

__device__ __forceinline__ void gload_lds16(const void* g, void* l) {
  __builtin_amdgcn_global_load_lds((const __attribute__((address_space(1))) unsigned*)g,
                                   (__attribute__((address_space(3))) unsigned*)l, 16, 0, 0);
}

// ---------------- fused fp32 -> bf16 convert for x, W_qkv, W_o ----------------
__global__ __launch_bounds__(256) void cvt_all(const float* __restrict__ x, const float* __restrict__ wqkv,
                                               const float* __restrict__ wo, u16* __restrict__ xb,
                                               u16* __restrict__ wqkvb, u16* __restrict__ wob) {
  int i = blockIdx.x * 256 + threadIdx.x;  // 2M quads total
  const float* src; u16* dst; int off;
  if (i < 1048576) { src = x; dst = xb; off = i; }
  else if (i < 1048576 + 786432) { src = wqkv; dst = wqkvb; off = i - 1048576; }
  else { src = wo; dst = wob; off = i - (1048576 + 786432); }
  float4 v = *(const float4*)(src + (size_t)off * 4);
  unsigned lo = f2bf(v.x) | ((unsigned)f2bf(v.y) << 16);
  unsigned hi = f2bf(v.z) | ((unsigned)f2bf(v.w) << 16);
  uint2 w; w.x = lo; w.y = hi;
  *(uint2*)(dst + (size_t)off * 4) = w;
}

// ---------------- fused QKV GEMM (128x128, BK=64, XOR swizzle) + RoPE + packing ----------------
// blockIdx.y: 0-7 -> Q cols, 8-15 -> K cols, 16-23 -> V cols. The epilogue rotates
// (Q,K) / transposes (V) and stores directly into the attn fragment layouts.
// Q pre-scaled by 0.125*log2(e) (log2-domain softmax downstream).
__global__ __launch_bounds__(256) void gemm_qkv_fused(const u16* __restrict__ A, const u16* __restrict__ B,
                                                      const int* __restrict__ pos, u16* __restrict__ Qf,
                                                      u16* __restrict__ Kf, u16* __restrict__ Vf) {
  __shared__ u16 As[128 * 64];  // 16 KB
  __shared__ u16 Bs[128 * 64];  // 16 KB
  const int K = 1024;
  const int tid = threadIdx.x;
  const int wave = tid >> 6;
  const int lane = tid & 63;
  const int m0 = blockIdx.x * 128;
  const int n0 = blockIdx.y * 128;
  const int wm = (wave >> 1) * 64;
  const int wn = (wave & 1) * 64;

  f32x4 acc[4][4];
#pragma unroll
  for (int m = 0; m < 4; ++m)
#pragma unroll
    for (int n = 0; n < 4; ++n) acc[m][n] = (f32x4){0.f, 0.f, 0.f, 0.f};

  const int srow = lane >> 3;
  const int sslot = lane & 7;
  const int fr = lane & 15;
  const int fk = lane >> 4;
  const int fg = lane >> 4;

  for (int k0 = 0; k0 < K; k0 += 64) {
    __syncthreads();
#pragma unroll
    for (int q = 0; q < 4; ++q) {
      int r = wave * 32 + q * 8 + srow;
      int src_slot = sslot ^ (r & 7);
      gload_lds16(A + (size_t)(m0 + r) * K + k0 + src_slot * 8, As + r * 64 + sslot * 8);
      gload_lds16(B + (size_t)(n0 + r) * K + k0 + src_slot * 8, Bs + r * 64 + sslot * 8);
    }
    __syncthreads();

#pragma unroll
    for (int kk = 0; kk < 2; ++kk) {
      short8 af[4], bf[4];
#pragma unroll
      for (int m = 0; m < 4; ++m) {
        int r = wm + m * 16 + fr;
        af[m] = *(const short8*)(As + r * 64 + (((kk * 4 + fk) ^ (r & 7)) << 3));
      }
#pragma unroll
      for (int n = 0; n < 4; ++n) {
        int r = wn + n * 16 + fr;
        bf[n] = *(const short8*)(Bs + r * 64 + (((kk * 4 + fk) ^ (r & 7)) << 3));
      }
#pragma unroll
      for (int m = 0; m < 4; ++m)
#pragma unroll
        for (int n = 0; n < 4; ++n)
          acc[m][n] = __builtin_amdgcn_mfma_f32_16x16x32_bf16(af[m], bf[n], acc[m][n], 0, 0, 0);
    }
  }

  // ---- fused epilogue ----
  // lane element (m,n,r): row sg = m0+wm+m*16+fg*4+r, col = n0+wn+n*16+fr.
  // d = col&63 = n*16+fr; h = ((n0+wn)>>6)&15; PER-BH tile t = (row>>5)&63.
  const int h = ((n0 + wn) >> 6) & 15;
  const int ny = blockIdx.y;

  if (ny < 16) {
    // ---- Q or K: interleaved RoPE; pair (d even, d odd) = lanes (fr, fr^1) ----
    u16* __restrict__ dst = (ny < 8) ? Qf : Kf;
    const float scale = (ny < 8) ? 0.18033688011112043f : 1.0f;  // 0.125*log2(e) for Q
#pragma unroll
    for (int n = 0; n < 4; ++n) {
      const int d = n * 16 + fr;
      const float f = __builtin_exp2f(-(float)(d >> 1) * 0.41524101186f);
      const int j = n;
      const int lofs = 32 * (fr >> 3);
      const int e = fr & 7;
#pragma unroll
      for (int m = 0; m < 4; ++m) {
        const int t = ((m0 + wm + m * 16) >> 5) & 63;  // per-bh tile (FIX)
#pragma unroll
        for (int r = 0; r < 4; ++r) {
          const int sg = m0 + wm + m * 16 + fg * 4 + r;
          float p = (float)pos[sg];
          float sn, cs;
          __sincosf(p * f, &sn, &cs);
          float v = acc[m][n][r];
          float vpart = __shfl_xor(v, 1);
          float oe = (cs * v - sn * vpart) * scale;
          float oo = (sn * v + cs * vpart) * scale;
          if (!(fr & 1)) {
            unsigned w = f2bf(oe) | ((unsigned)f2bf(oo) << 16);
            int bh = ((sg >> 11) << 4) + h;
            *(unsigned*)(dst + (size_t)bh * 131072 + t * 2048 + j * 512 +
                         ((sg & 31) + lofs) * 8 + e) = w;
          }
        }
      }
    }
  } else {
    // ---- V: transpose into Vf fragments; lanes fg, fg^1 pair via shfl_xor(16) ----
#pragma unroll
    for (int n = 0; n < 4; ++n) {
      const int d = n * 16 + fr;
      const int seg_hi = (d >> 5) << 1;
      const int l = (d & 31) + 32 * (fg >> 1);
#pragma unroll
      for (int m = 0; m < 4; ++m) {
        const int sgb = m0 + wm + m * 16;
        const int t = (sgb >> 5) & 63;  // per-bh tile (FIX)
        const int seg = seg_hi | (m & 1);
        unsigned lo = f2bf(acc[m][n][0]) | ((unsigned)f2bf(acc[m][n][1]) << 16);
        unsigned hi2 = f2bf(acc[m][n][2]) | ((unsigned)f2bf(acc[m][n][3]) << 16);
        unsigned plo = __shfl_xor(lo, 16);
        unsigned phi = __shfl_xor(hi2, 16);
        if (!(fg & 1)) {
          int bh = ((sgb >> 11) << 4) + h;
          uint4 w; w.x = lo; w.y = hi2; w.z = plo; w.w = phi;
          *(uint4*)(Vf + (size_t)bh * 131072 + t * 2048 + seg * 512 + l * 8) = w;
        }
      }
    }
  }
}

// ---------------- GEMM 64x128, BK=64, XOR-swizzled (O-projection) ----------------
template <typename OutT>
__global__ __launch_bounds__(256) void gemm_bt64_2(const u16* __restrict__ A, const u16* __restrict__ B,
                                                   OutT* __restrict__ C, int M, int N, int K) {
  __shared__ u16 As[64 * 64];    // 8 KB
  __shared__ u16 Bs[128 * 64];   // 16 KB
  const int tid = threadIdx.x;
  const int wave = tid >> 6;
  const int lane = tid & 63;
  const int m0 = blockIdx.x * 64;
  const int n0 = blockIdx.y * 128;
  const int wm = (wave >> 1) * 32;
  const int wn = (wave & 1) * 64;

  f32x4 acc[2][4];
#pragma unroll
  for (int m = 0; m < 2; ++m)
#pragma unroll
    for (int n = 0; n < 4; ++n) acc[m][n] = (f32x4){0.f, 0.f, 0.f, 0.f};

  const int srow = lane >> 3;
  const int sslot = lane & 7;
  const int fr = lane & 15;
  const int fk = lane >> 4;

  for (int k0 = 0; k0 < K; k0 += 64) {
    __syncthreads();
#pragma unroll
    for (int q = 0; q < 2; ++q) {  // A: 16 rows per wave
      int r = wave * 16 + q * 8 + srow;
      int src_slot = sslot ^ (r & 7);
      gload_lds16(A + (size_t)(m0 + r) * K + k0 + src_slot * 8, As + r * 64 + sslot * 8);
    }
#pragma unroll
    for (int q = 0; q < 4; ++q) {  // B: 32 rows per wave
      int r = wave * 32 + q * 8 + srow;
      int src_slot = sslot ^ (r & 7);
      gload_lds16(B + (size_t)(n0 + r) * K + k0 + src_slot * 8, Bs + r * 64 + sslot * 8);
    }
    __syncthreads();

#pragma unroll
    for (int kk = 0; kk < 2; ++kk) {
      short8 af[2], bf[4];
#pragma unroll
      for (int m = 0; m < 2; ++m) {
        int r = wm + m * 16 + fr;
        af[m] = *(const short8*)(As + r * 64 + (((kk * 4 + fk) ^ (r & 7)) << 3));
      }
#pragma unroll
      for (int n = 0; n < 4; ++n) {
        int r = wn + n * 16 + fr;
        bf[n] = *(const short8*)(Bs + r * 64 + (((kk * 4 + fk) ^ (r & 7)) << 3));
      }
#pragma unroll
      for (int m = 0; m < 2; ++m)
#pragma unroll
        for (int n = 0; n < 4; ++n)
          acc[m][n] = __builtin_amdgcn_mfma_f32_16x16x32_bf16(af[m], bf[n], acc[m][n], 0, 0, 0);
    }
  }

  const int fg = lane >> 4;
#pragma unroll
  for (int m = 0; m < 2; ++m)
#pragma unroll
    for (int n = 0; n < 4; ++n)
#pragma unroll
      for (int r = 0; r < 4; ++r) {
        int row = m0 + wm + m * 16 + fg * 4 + r;
        int col = n0 + wn + n * 16 + fr;
        if constexpr (sizeof(OutT) == 2)
          C[(size_t)row * N + col] = (OutT)f2bf(acc[m][n][r]);
        else
          C[(size_t)row * N + col] = (OutT)acc[m][n][r];
      }
}

// ---------------- causal flash attention v6: packed-fragment coalesced loads ----------------
__global__ __launch_bounds__(256, 2) void attn6(const u16* __restrict__ Qf, const u16* __restrict__ Kf,
                                                const u16* __restrict__ Vf, u16* __restrict__ Ao) {
  __shared__ float smM[3][64], smL[3][64];
  __shared__ float smO[3][64][33];
  const int tid = threadIdx.x;
  const int lane = tid & 63;
  const int wid = tid >> 6;
  const int bid = blockIdx.x;            // 2048 = 8 xcd * 4 bh * 64 qt
  const int xcd = bid & 7;
  const int rr = bid >> 3;
  const int bh = xcd * 4 + (rr & 3);
  const int qt = 63 - (rr >> 2);
  const int q0 = qt * 32;
  const u16* __restrict__ Qp = Qf + (size_t)bh * 131072;
  const u16* __restrict__ Kp = Kf + (size_t)bh * 131072;
  const u16* __restrict__ Vp = Vf + (size_t)bh * 131072;
  const int lq = lane & 31;
  const int hi = lane >> 5;

  const u16* qb = Qp + (size_t)qt * 2048 + lane * 8;
  short8 qf0 = *(const short8*)(qb);
  short8 qf1 = *(const short8*)(qb + 512);
  short8 qf2 = *(const short8*)(qb + 1024);
  short8 qf3 = *(const short8*)(qb + 1536);

  f32x16 o0, o1;
#pragma unroll
  for (int r = 0; r < 16; ++r) { o0[r] = 0.f; o1[r] = 0.f; }
  float m = -1e30f, lsum = 0.f;

  const int nkt = qt + 1;
  const int base = nkt >> 2, rem = nkt & 3;
  const int cnt = base + (wid < rem ? 1 : 0);
  const int beg = wid * base + (wid < rem ? wid : rem);

  if (cnt > 0) {
    const u16* kp = Kp + (size_t)beg * 2048 + lane * 8;
    const u16* vp = Vp + (size_t)beg * 2048 + lane * 8;
    short8 kc0 = *(const short8*)(kp);
    short8 kc1 = *(const short8*)(kp + 512);
    short8 kc2 = *(const short8*)(kp + 1024);
    short8 kc3 = *(const short8*)(kp + 1536);
    short8 vc0 = *(const short8*)(vp);
    short8 vc1 = *(const short8*)(vp + 512);
    short8 vc2 = *(const short8*)(vp + 1024);
    short8 vc3 = *(const short8*)(vp + 1536);

    for (int i = 0; i < cnt; ++i) {
      const int kt = beg + i;
      const int ktn = beg + (i + 1 < cnt ? i + 1 : i);
      const u16* kpn = Kp + (size_t)ktn * 2048 + lane * 8;
      const u16* vpn = Vp + (size_t)ktn * 2048 + lane * 8;
      short8 kn0 = *(const short8*)(kpn);
      short8 kn1 = *(const short8*)(kpn + 512);
      short8 kn2 = *(const short8*)(kpn + 1024);
      short8 kn3 = *(const short8*)(kpn + 1536);
      short8 vn0 = *(const short8*)(vpn);
      short8 vn1 = *(const short8*)(vpn + 512);
      short8 vn2 = *(const short8*)(vpn + 1024);
      short8 vn3 = *(const short8*)(vpn + 1536);

      f32x16 sc;
#pragma unroll
      for (int r = 0; r < 16; ++r) sc[r] = 0.f;
      __builtin_amdgcn_s_setprio(1);
      sc = __builtin_amdgcn_mfma_f32_32x32x16_bf16(kc0, qf0, sc, 0, 0, 0);
      sc = __builtin_amdgcn_mfma_f32_32x32x16_bf16(kc1, qf1, sc, 0, 0, 0);
      sc = __builtin_amdgcn_mfma_f32_32x32x16_bf16(kc2, qf2, sc, 0, 0, 0);
      sc = __builtin_amdgcn_mfma_f32_32x32x16_bf16(kc3, qf3, sc, 0, 0, 0);
      __builtin_amdgcn_s_setprio(0);

      if (kt == qt) {
#pragma unroll
        for (int r = 0; r < 16; ++r) {
          int ko = (r & 3) + 8 * (r >> 2) + 4 * hi;
          sc[r] = (ko <= lq) ? sc[r] : -1e30f;
        }
      }

      float t0 = fmaxf(fmaxf(sc[0], sc[1]), sc[2]);
      float t1 = fmaxf(fmaxf(sc[3], sc[4]), sc[5]);
      float t2 = fmaxf(fmaxf(sc[6], sc[7]), sc[8]);
      float t3 = fmaxf(fmaxf(sc[9], sc[10]), sc[11]);
      float t4 = fmaxf(fmaxf(sc[12], sc[13]), sc[14]);
      float t5 = fmaxf(fmaxf(t0, t1), sc[15]);
      float t6 = fmaxf(fmaxf(t2, t3), t4);
      float pmax = xhalf_max(fmaxf(t5, t6));

      if (!__all(pmax - m <= 11.5f)) {
        float nm = fmaxf(m, pmax);
        float alpha = __builtin_exp2f(m - nm);
        lsum *= alpha;
#pragma unroll
        for (int r = 0; r < 16; ++r) { o0[r] *= alpha; o1[r] *= alpha; }
        m = nm;
      }

#pragma unroll
      for (int r = 0; r < 16; ++r) sc[r] = __builtin_exp2f(sc[r] - m);
      float r8[8];
#pragma unroll
      for (int r = 0; r < 8; ++r) r8[r] = sc[r] + sc[r + 8];
#pragma unroll
      for (int s = 4; s >= 1; s >>= 1)
#pragma unroll
        for (int r = 0; r < s; ++r) r8[r] += r8[r + s];
      lsum += xhalf_sum(r8[0]);

      unsigned w[8];
#pragma unroll
      for (int t = 0; t < 8; ++t) {
        unsigned d;
        asm("v_cvt_pk_bf16_f32 %0, %1, %2" : "=v"(d) : "v"(sc[2 * t]), "v"(sc[2 * t + 1]));
        w[t] = d;
      }
      short8 pb0, pb1;
      {
        uint2v r1 = __builtin_amdgcn_permlane32_swap(w[0], w[2], false, false);
        uint2v r2 = __builtin_amdgcn_permlane32_swap(w[1], w[3], false, false);
        unsigned r1x = r1.x, r1y = r1.y, r2x = r2.x, r2y = r2.y;
        uint4v t4v; t4v.x = r1x; t4v.y = r2x; t4v.z = r1y; t4v.w = r2y;
        pb0 = __builtin_bit_cast(short8, t4v);
        uint2v r3 = __builtin_amdgcn_permlane32_swap(w[4], w[6], false, false);
        uint2v r4 = __builtin_amdgcn_permlane32_swap(w[5], w[7], false, false);
        unsigned r3x = r3.x, r3y = r3.y, r4x = r4.x, r4y = r4.y;
        uint4v t5v; t5v.x = r3x; t5v.y = r4x; t5v.z = r3y; t5v.w = r4y;
        pb1 = __builtin_bit_cast(short8, t5v);
      }

      __builtin_amdgcn_s_setprio(1);
      o0 = __builtin_amdgcn_mfma_f32_32x32x16_bf16(vc0, pb0, o0, 0, 0, 0);
      o0 = __builtin_amdgcn_mfma_f32_32x32x16_bf16(vc1, pb1, o0, 0, 0, 0);
      o1 = __builtin_amdgcn_mfma_f32_32x32x16_bf16(vc2, pb0, o1, 0, 0, 0);
      o1 = __builtin_amdgcn_mfma_f32_32x32x16_bf16(vc3, pb1, o1, 0, 0, 0);
      __builtin_amdgcn_s_setprio(0);

      kc0 = kn0; kc1 = kn1; kc2 = kn2; kc3 = kn3;
      vc0 = vn0; vc1 = vn1; vc2 = vn2; vc3 = vn3;
    }
  }

  if (wid != 0) {
    smM[wid - 1][lane] = m;
    smL[wid - 1][lane] = lsum;
#pragma unroll
    for (int r = 0; r < 16; ++r) smO[wid - 1][lane][r] = o0[r];
#pragma unroll
    for (int r = 0; r < 16; ++r) smO[wid - 1][lane][16 + r] = o1[r];
  }
  __syncthreads();
  if (wid == 0) {
    float m1 = smM[0][lane], m2 = smM[1][lane], m3 = smM[2][lane];
    float M = fmaxf(fmaxf(m, m1), fmaxf(m2, m3));
    float a0 = __builtin_exp2f(m - M);
    float a1 = __builtin_exp2f(m1 - M);
    float a2 = __builtin_exp2f(m2 - M);
    float a3 = __builtin_exp2f(m3 - M);
    float L = lsum * a0 + smL[0][lane] * a1 + smL[1][lane] * a2 + smL[2][lane] * a3;
    float inv = 1.f / L;
    const int b = bh >> 4, h = bh & 15;
    u16* outp = Ao + ((size_t)(b << 11) + q0 + lq) * 1024 + h * 64;
#pragma unroll
    for (int g = 0; g < 4; ++g) {
      int d = 8 * g + 4 * hi;
      float c[8];
#pragma unroll
      for (int j = 0; j < 4; ++j) {
        c[j] = (o0[4 * g + j] * a0 + smO[0][lane][4 * g + j] * a1 +
                smO[1][lane][4 * g + j] * a2 + smO[2][lane][4 * g + j] * a3) * inv;
        c[4 + j] = (o1[4 * g + j] * a0 + smO[0][lane][16 + 4 * g + j] * a1 +
                    smO[1][lane][16 + 4 * g + j] * a2 + smO[2][lane][16 + 4 * g + j] * a3) * inv;
      }
      uint2v w0;
      w0.x = f2bf(c[0]) | ((unsigned)f2bf(c[1]) << 16);
      w0.y = f2bf(c[2]) | ((unsigned)f2bf(c[3]) << 16);
      *(uint2v*)(outp + d) = w0;
      uint2v w1;
      w1.x = f2bf(c[4]) | ((unsigned)f2bf(c[5]) << 16);
      w1.y = f2bf(c[6]) | ((unsigned)f2bf(c[7]) << 16);
      *(uint2v*)(outp + 32 + d) = w1;
    }
  }
}

extern "C" void kernel_launch(void* const* d_in, const int* in_sizes, int n_in,
                              void* d_out, int out_size, void* d_ws, size_t ws_size,
                              hipStream_t stream) {
  const float* x = (const float*)d_in[0];
  const int* pos = (const int*)d_in[1];
  const float* Wqkv = (const float*)d_in[2];
  const float* Wo = (const float*)d_in[3];
  float* out = (float*)d_out;

  char* ws = (char*)d_ws;
  const size_t MB = 1024 * 1024;
  u16* xb     = (u16*)(ws);             //  8 MB: [4096,1024]
  u16* wqkvb  = (u16*)(ws + 8 * MB);    //  6 MB: [3072,1024]
  u16* wob    = (u16*)(ws + 14 * MB);   //  2 MB: [1024,1024]
  u16* Qf     = (u16*)(ws + 16 * MB);   //  8 MB packed fragments (pre-scaled 0.125*log2e)
  u16* Kf     = (u16*)(ws + 24 * MB);   //  8 MB packed fragments
  u16* Vf     = (u16*)(ws + 32 * MB);   //  8 MB packed fragments
  u16* ao     = (u16*)(ws + 40 * MB);   //  8 MB: [4096,1024]

  cvt_all<<<8192, 256, 0, stream>>>(x, Wqkv, Wo, xb, wqkvb, wob);
  gemm_qkv_fused<<<dim3(32, 24), 256, 0, stream>>>(xb, wqkvb, pos, Qf, Kf, Vf);
  attn6<<<2048, 256, 0, stream>>>(Qf, Kf, Vf, ao);
  gemm_bt64_2<float><<<dim3(64, 8), 256, 0, stream>>>(ao, wob, out, 4096, 1024, 1024);
}